// Round 1
// baseline (344.451 us; speedup 1.0000x reference)
//
#include <hip/hip_runtime.h>

// ExpFlow: scaling-and-squaring exponentiation of a velocity field.
// x: [N=2, C=3, 128^3] f32. u0 = x/32; 5x: u <- u + warp(u, id+u).
//
// R8: padded-AoS (float4/voxel) intermediate layout.
// Diagnosis from R7 counters: all 5 steps ~60us with HBM 17%, VALU 14%,
// occupancy 52% -> bound by the vector-memory path of the gathers
// (~41 cyc per VMEM instr per CU). In SoA each trilinear corner costs 3
// separate 8B loads into 3 distinct cache lines (one per channel plane).
// AoS4 [N,D,H,W,4] makes a corner-pair (x0,x0+1) = two aligned float4
// loads carrying ALL channels: 20 VMEM instrs/thread instead of 30 and
// ~3x fewer distinct line-touches on the gather path.
//
// Pipeline: s1 SoA(x, scale fused)->AoS4 A; s2..s4 AoS4<->AoS4 (A,B in
// d_ws, 2 x 64 MiB = 134,217,728 B, proven fit in R5); s5 AoS4->SoA d_out
// (written exactly once). Grid/XCD-slab swizzle and lerp arithmetic are
// bit-identical to the verified R7 kernel.

namespace {
constexpr int kD = 128, kH = 128, kW = 128, kN = 2, kC = 3;
constexpr int kPlane = kD * kH * kW;        // 2^21
constexpr int kVol   = kC * kPlane;
constexpr int kTotalVox   = kN * kPlane;
constexpr int kTotalElems = kN * kVol;      // 12,582,912 floats (SoA buffer)
constexpr int kAosElems   = kN * kPlane * 4; // 16,777,216 floats (AoS4 buffer)
constexpr float kScale0 = 1.0f / 32.0f;
}

typedef float f32x2 __attribute__((ext_vector_type(2)));
typedef float f32x4 __attribute__((ext_vector_type(4)));

// ---------------------------------------------------------------------------
// R8 kernel. MODE 0: SoA x (scaled) -> AoS4; 1: AoS4 -> AoS4; 2: AoS4 -> SoA.
// ---------------------------------------------------------------------------
template <int MODE>
__global__ __launch_bounds__(256) void step_aos(const float* __restrict__ u,
                                                float* __restrict__ out) {
    // XCD-slab swizzle (identical to R7): 8192 blocks; b&7 = XCD; 16 slabs
    // (2 batches x 8 d-slabs of 16 planes); XCD j owns slabs j, j+8 swept
    // sequentially so gathers hit a ~2.7MB window in its private L2.
    int b    = blockIdx.x;
    int xcd  = b & 7;
    int seq  = b >> 3;                    // 0..1023
    int slab = xcd | ((seq >> 9) << 3);   // 0..15
    int n    = slab >> 3;                 // batch
    int dblk = slab & 7;                  // d-slab within batch
    int vo   = ((seq & 511) << 9) | (threadIdx.x << 1);
    int rr   = (dblk << 18) | vo;         // within-batch plane-linear voxel

    int w = rr & 127;
    int h = (rr >> 7) & 127;
    int d = rr >> 14;

    const float* __restrict__ ubs = u + (size_t)n * kVol;            // SoA base
    const float* __restrict__ uba = u + ((size_t)n * kPlane << 2);   // AoS4 base

    // Base velocity for voxels (rr, rr+1), channels x/y/z.
    float vx[2], vy[2], vz[2];
    if constexpr (MODE == 0) {
        f32x2 bx = *(const f32x2*)(ubs + rr);
        f32x2 by = *(const f32x2*)(ubs + kPlane + rr);
        f32x2 bz = *(const f32x2*)(ubs + 2 * kPlane + rr);
        bx *= kScale0; by *= kScale0; bz *= kScale0;
        vx[0] = bx.x; vx[1] = bx.y;
        vy[0] = by.x; vy[1] = by.y;
        vz[0] = bz.x; vz[1] = bz.y;
    } else {
        const float* ua = uba + ((size_t)rr << 2);
        f32x4 q0 = *(const f32x4*)(ua);
        f32x4 q1 = *(const f32x4*)(ua + 4);
        vx[0] = q0.x; vy[0] = q0.y; vz[0] = q0.z;
        vx[1] = q1.x; vy[1] = q1.y; vz[1] = q1.z;
    }

    // Cube offsets + weights (border clamp folded into low corner).
    int   o[2];
    float wxa[2], wya[2], wza[2];
    #pragma unroll
    for (int j = 0; j < 2; ++j) {
        float px = fminf(fmaxf((float)(w + j) + vx[j] * 63.5f, 0.0f), 127.0f);
        float py = fminf(fmaxf((float)h       + vy[j] * 63.5f, 0.0f), 127.0f);
        float pz = fminf(fmaxf((float)d       + vz[j] * 63.5f, 0.0f), 127.0f);
        int x0 = min((int)floorf(px), 126);
        int y0 = min((int)floorf(py), 126);
        int z0 = min((int)floorf(pz), 126);
        wxa[j] = px - (float)x0;
        wya[j] = py - (float)y0;
        wza[j] = pz - (float)z0;
        o[j] = (z0 << 14) + (y0 << 7) + x0;
    }

    float res[3][2];
    if constexpr (MODE == 0) {
        // SoA gathers from x (scaled) — identical to R7 SCALED path.
        const int rowoff[4] = {0, 128, 16384, 16512};
        #pragma unroll
        for (int j = 0; j < 2; ++j) {
            float wx = wxa[j], wy = wya[j], wz = wza[j];
            float omx = 1.0f - wx, omy = 1.0f - wy, omz = 1.0f - wz;
            #pragma unroll
            for (int c = 0; c < 3; ++c) {
                const float* __restrict__ up = ubs + c * kPlane;
                f32x2 v00 = *(const f32x2*)(up + o[j] + rowoff[0]);
                f32x2 v01 = *(const f32x2*)(up + o[j] + rowoff[1]);
                f32x2 v10 = *(const f32x2*)(up + o[j] + rowoff[2]);
                f32x2 v11 = *(const f32x2*)(up + o[j] + rowoff[3]);
                v00 *= kScale0; v01 *= kScale0; v10 *= kScale0; v11 *= kScale0;
                float c00 = v00.x * omx + v00.y * wx;
                float c01 = v01.x * omx + v01.y * wx;
                float c10 = v10.x * omx + v10.y * wx;
                float c11 = v11.x * omx + v11.y * wx;
                float c0 = c00 * omy + c01 * wy;
                float c1 = c10 * omy + c11 * wy;
                float base = (c == 0) ? vx[j] : (c == 1) ? vy[j] : vz[j];
                res[c][j] = base + (c0 * omz + c1 * wz);
            }
        }
    } else {
        // AoS4 gathers: per corner-pair one 32B region = 2 aligned float4
        // loads carrying all channels. 8 gather instrs per voxel vs 12 SoA,
        // and channels share cache lines (~3x fewer line-touches).
        #pragma unroll
        for (int j = 0; j < 2; ++j) {
            const float* __restrict__ pb = uba + ((size_t)o[j] << 2);
            f32x4 a00 = *(const f32x4*)(pb);
            f32x4 b00 = *(const f32x4*)(pb + 4);
            f32x4 a01 = *(const f32x4*)(pb + 512);    // y0+1 row
            f32x4 b01 = *(const f32x4*)(pb + 516);
            f32x4 a10 = *(const f32x4*)(pb + 65536);  // z0+1 row
            f32x4 b10 = *(const f32x4*)(pb + 65540);
            f32x4 a11 = *(const f32x4*)(pb + 66048);  // z0+1, y0+1 row
            f32x4 b11 = *(const f32x4*)(pb + 66052);
            float wx = wxa[j], wy = wya[j], wz = wza[j];
            float omx = 1.0f - wx, omy = 1.0f - wy, omz = 1.0f - wz;
            #pragma unroll
            for (int c = 0; c < 3; ++c) {
                float c00 = a00[c] * omx + b00[c] * wx;
                float c01 = a01[c] * omx + b01[c] * wx;
                float c10 = a10[c] * omx + b10[c] * wx;
                float c11 = a11[c] * omx + b11[c] * wx;
                float c0 = c00 * omy + c01 * wy;
                float c1 = c10 * omy + c11 * wy;
                float base = (c == 0) ? vx[j] : (c == 1) ? vy[j] : vz[j];
                res[c][j] = base + (c0 * omz + c1 * wz);
            }
        }
    }

    if constexpr (MODE == 2) {
        // Final step: SoA store into d_out (written exactly once).
        float* __restrict__ ob = out + (size_t)n * kVol;
        *(f32x2*)(ob + rr)              = f32x2{res[0][0], res[0][1]};
        *(f32x2*)(ob + kPlane + rr)     = f32x2{res[1][0], res[1][1]};
        *(f32x2*)(ob + 2 * kPlane + rr) = f32x2{res[2][0], res[2][1]};
    } else {
        float* __restrict__ oa = out + ((size_t)n * kPlane << 2) + ((size_t)rr << 2);
        *(f32x4*)(oa)     = f32x4{res[0][0], res[1][0], res[2][0], 0.0f};
        *(f32x4*)(oa + 4) = f32x4{res[0][1], res[1][1], res[2][1], 0.0f};
    }
}

// ---------------------------------------------------------------------------
// R7 SoA kernel retained verbatim as the small-workspace fallback.
// ---------------------------------------------------------------------------
template <bool SCALED>
__global__ __launch_bounds__(256) void step_kernel(const float* __restrict__ u,
                                                   float* __restrict__ out) {
    int b    = blockIdx.x;
    int xcd  = b & 7;
    int seq  = b >> 3;
    int slab = xcd | ((seq >> 9) << 3);
    int n    = slab >> 3;
    int dblk = slab & 7;
    int vo   = ((seq & 511) << 9) | (threadIdx.x << 1);
    int rr   = (dblk << 18) | vo;

    int w = rr & 127;
    int h = (rr >> 7) & 127;
    int d = rr >> 14;

    const float* __restrict__ ub = u + (size_t)n * kVol;

    f32x2 bx = *(const f32x2*)(ub + rr);
    f32x2 by = *(const f32x2*)(ub + kPlane + rr);
    f32x2 bz = *(const f32x2*)(ub + 2 * kPlane + rr);
    if (SCALED) { bx *= kScale0; by *= kScale0; bz *= kScale0; }

    int   o[2];
    float wxa[2], wya[2], wza[2];
    #pragma unroll
    for (int j = 0; j < 2; ++j) {
        float vx = (j == 0) ? bx.x : bx.y;
        float vy = (j == 0) ? by.x : by.y;
        float vz = (j == 0) ? bz.x : bz.y;
        float px = fminf(fmaxf((float)(w + j) + vx * 63.5f, 0.0f), 127.0f);
        float py = fminf(fmaxf((float)h       + vy * 63.5f, 0.0f), 127.0f);
        float pz = fminf(fmaxf((float)d       + vz * 63.5f, 0.0f), 127.0f);
        int x0 = min((int)floorf(px), 126);
        int y0 = min((int)floorf(py), 126);
        int z0 = min((int)floorf(pz), 126);
        wxa[j] = px - (float)x0;
        wya[j] = py - (float)y0;
        wza[j] = pz - (float)z0;
        o[j] = (z0 << 14) + (y0 << 7) + x0;
    }

    const int rowoff[4] = {0, 128, 16384, 16512};
    float res[3][2];
    #pragma unroll
    for (int j = 0; j < 2; ++j) {
        float wx = wxa[j], wy = wya[j], wz = wza[j];
        float omx = 1.0f - wx, omy = 1.0f - wy, omz = 1.0f - wz;
        #pragma unroll
        for (int c = 0; c < 3; ++c) {
            const float* __restrict__ up = ub + c * kPlane;
            f32x2 v00 = *(const f32x2*)(up + o[j] + rowoff[0]);
            f32x2 v01 = *(const f32x2*)(up + o[j] + rowoff[1]);
            f32x2 v10 = *(const f32x2*)(up + o[j] + rowoff[2]);
            f32x2 v11 = *(const f32x2*)(up + o[j] + rowoff[3]);
            if (SCALED) { v00 *= kScale0; v01 *= kScale0; v10 *= kScale0; v11 *= kScale0; }
            float c00 = v00.x * omx + v00.y * wx;
            float c01 = v01.x * omx + v01.y * wx;
            float c10 = v10.x * omx + v10.y * wx;
            float c11 = v11.x * omx + v11.y * wx;
            float c0 = c00 * omy + c01 * wy;
            float c1 = c10 * omy + c11 * wy;
            float s  = c0 * omz + c1 * wz;
            float base = (c == 0) ? ((j == 0) ? bx.x : bx.y)
                       : (c == 1) ? ((j == 0) ? by.x : by.y)
                                  : ((j == 0) ? bz.x : bz.y);
            res[c][j] = base + s;
        }
    }

    float* __restrict__ ob = out + (size_t)n * kVol;
    *(f32x2*)(ob + rr)              = f32x2{res[0][0], res[0][1]};
    *(f32x2*)(ob + kPlane + rr)     = f32x2{res[1][0], res[1][1]};
    *(f32x2*)(ob + 2 * kPlane + rr) = f32x2{res[2][0], res[2][1]};
}

extern "C" void kernel_launch(void* const* d_in, const int* in_sizes, int n_in,
                              void* d_out, int out_size, void* d_ws, size_t ws_size,
                              hipStream_t stream) {
    const float* x = (const float*)d_in[0];
    float* out = (float*)d_out;
    float* ws  = (float*)d_ws;

    const int grd = kTotalVox / (256 * 2);   // 8192 blocks
    const size_t need_aos = (size_t)2 * kAosElems * sizeof(float);    // 134,217,728 B
    const size_t need_soa = (size_t)2 * kTotalElems * sizeof(float);  // 100.7 MB

    if (ws_size >= need_aos) {
        float* A = ws;
        float* B = ws + (size_t)kAosElems;
        step_aos<0><<<grd, 256, 0, stream>>>(x, A);    // s1: SoA x -> AoS4 (scale fused)
        step_aos<1><<<grd, 256, 0, stream>>>(A, B);    // s2
        step_aos<1><<<grd, 256, 0, stream>>>(B, A);    // s3
        step_aos<1><<<grd, 256, 0, stream>>>(A, B);    // s4
        step_aos<2><<<grd, 256, 0, stream>>>(B, out);  // s5: AoS4 -> SoA d_out (once)
    } else if (ws_size >= need_soa) {
        // R7 SoA ping-pong fallback.
        float* A = ws;
        float* B = ws + (size_t)kTotalElems;
        step_kernel<true ><<<grd, 256, 0, stream>>>(x, A);
        step_kernel<false><<<grd, 256, 0, stream>>>(A, B);
        step_kernel<false><<<grd, 256, 0, stream>>>(B, A);
        step_kernel<false><<<grd, 256, 0, stream>>>(A, B);
        step_kernel<false><<<grd, 256, 0, stream>>>(B, out);
    } else {
        // R3-parity fallback: x->out->ws->out->ws->out.
        step_kernel<true ><<<grd, 256, 0, stream>>>(x,   out);
        step_kernel<false><<<grd, 256, 0, stream>>>(out, ws);
        step_kernel<false><<<grd, 256, 0, stream>>>(ws,  out);
        step_kernel<false><<<grd, 256, 0, stream>>>(out, ws);
        step_kernel<false><<<grd, 256, 0, stream>>>(ws,  out);
    }
}